// Round 3
// baseline (1298.524 us; speedup 1.0000x reference)
//
#include <hip/hip_runtime.h>

#define B_ 8
#define N_ 2048
#define K_ 16
#define M_ (B_*N_)

// ------------------------------------------------------------------
// kNN: per (b,i) the 16 smallest ||x_i - x_j||^2 (direct differences,
// no cancellation -> ordering matches the fp64 reference).
// 32 rows/block, 8 lanes/row; per-lane sorted top-16 (u64 keys), merged
// across the 8 lanes with a shuffle + bitonic network (no LDS).
// ------------------------------------------------------------------
__device__ __forceinline__ unsigned long long kmin(unsigned long long a, unsigned long long b) {
    return a < b ? a : b;
}

template<int C>
__global__ __launch_bounds__(256, 2) void knn_kernel(const float* __restrict__ X,
                                                     int* __restrict__ idx_out) {
    constexpr int ROWS = 32, TPR = 8, TJ = 128;
    constexpr int SJ = (C == 3) ? 4 : (C + 4);   // padded LDS stride
    __shared__ float xj[TJ * SJ];

    int tid = threadIdx.x;
    int rlocal = tid / TPR;          // 0..31  row within block
    int r = tid & (TPR - 1);         // 0..7   lane within row
    int m = blockIdx.x * ROWS + rlocal;
    int b = m >> 11;
    int i = m & (N_ - 1);

    const float* xrow = X + (size_t)m * C;
    float xi[C];
#pragma unroll
    for (int c = 0; c < C; ++c) xi[c] = xrow[c];

    unsigned long long t[16];
#pragma unroll
    for (int q = 0; q < 16; ++q) t[q] = ~0ull;

    const float* Xb = X + (size_t)b * N_ * C;

    for (int jt = 0; jt < N_ / TJ; ++jt) {
        __syncthreads();                      // protect previous tile's readers
        if constexpr (C == 3) {
            for (int e = tid; e < TJ * 3; e += 256)
                xj[(e / 3) * 4 + (e % 3)] = Xb[jt * TJ * 3 + e];
        } else {
            constexpr int C4 = C / 4;
            const float4* src = (const float4*)(Xb + (size_t)jt * TJ * C);
            for (int e4 = tid; e4 < TJ * C4; e4 += 256) {
                int jl = e4 / C4, c4 = e4 % C4;
                *(float4*)&xj[jl * SJ + c4 * 4] = src[e4];
            }
        }
        __syncthreads();

#pragma unroll 2
        for (int jl = r; jl < TJ; jl += TPR) {
            float s = 0.f;
            if constexpr (C == 3) {
#pragma unroll
                for (int c = 0; c < 3; ++c) {
                    float df = xi[c] - xj[jl * SJ + c];
                    s = fmaf(df, df, s);
                }
            } else {
#pragma unroll
                for (int c4 = 0; c4 < C / 4; ++c4) {
                    float4 v = *(const float4*)&xj[jl * SJ + c4 * 4];
                    float d0 = xi[c4 * 4 + 0] - v.x;
                    float d1 = xi[c4 * 4 + 1] - v.y;
                    float d2 = xi[c4 * 4 + 2] - v.z;
                    float d3 = xi[c4 * 4 + 3] - v.w;
                    s = fmaf(d0, d0, s);
                    s = fmaf(d1, d1, s);
                    s = fmaf(d2, d2, s);
                    s = fmaf(d3, d3, s);
                }
            }
            int jg = jt * TJ + jl;
            unsigned u = __float_as_uint(s);
            u ^= (unsigned)(((int)u >> 31) | 0x80000000);   // monotone float->uint
            unsigned long long key = ((unsigned long long)u << 32) | (unsigned)jg;
            if (jg == i) key = ~0ull;                        // exclude self
            if (key < t[15]) {                               // sorted insert (static idx)
                t[15] = key;
#pragma unroll
                for (int s2 = 15; s2 > 0; --s2) {
                    unsigned long long a = t[s2 - 1], bb = t[s2];
                    bool sw = bb < a;
                    t[s2 - 1] = sw ? bb : a;
                    t[s2]     = sw ? a : bb;
                }
            }
        }
    }

    // merge the 8 lanes' sorted-16 lists: 3 rounds of bitonic split + re-sort
#pragma unroll
    for (int msk = 1; msk <= 4; msk <<= 1) {
        unsigned long long o[16];
#pragma unroll
        for (int q = 0; q < 16; ++q)
            o[q] = __shfl_xor((unsigned long long)t[q], msk, 64);
        unsigned long long nt[16];
#pragma unroll
        for (int q = 0; q < 16; ++q) nt[q] = kmin(t[q], o[15 - q]);  // lower half, bitonic
#pragma unroll
        for (int s2 = 8; s2 >= 1; s2 >>= 1) {
#pragma unroll
            for (int q = 0; q < 16; ++q) {
                if (!(q & s2)) {
                    unsigned long long a = nt[q], bb = nt[q | s2];
                    bool sw = bb < a;
                    nt[q]      = sw ? bb : a;
                    nt[q | s2] = sw ? a : bb;
                }
            }
        }
#pragma unroll
        for (int q = 0; q < 16; ++q) t[q] = nt[q];
    }

    if (r == 0) {
        int* op = idx_out + (size_t)m * K_;
#pragma unroll
        for (int q = 0; q < 16; ++q) op[q] = (int)(unsigned)(t[q] & 0xffffffffull);
    }
}

// ------------------------------------------------------------------
// t1 = X @ W_top  (rows 0..C-1 of W [2C, D]) in fp64 accumulation,
// stored as double.
// ------------------------------------------------------------------
template<int C, int D>
__global__ __launch_bounds__(256) void t1_kernel(const float* __restrict__ X,
                                                 const float* __restrict__ W,
                                                 double* __restrict__ T1) {
    constexpr int D4 = D / 4;
    int e4 = blockIdx.x * 256 + threadIdx.x;
    if (e4 >= M_ * D4) return;
    int m = e4 / D4, d4 = e4 - m * D4;
    const float* xr = X + (size_t)m * C;
    double a0 = 0.0, a1 = 0.0, a2 = 0.0, a3 = 0.0;
#pragma unroll
    for (int c = 0; c < C; ++c) {
        double a = (double)xr[c];
        float4 w = *(const float4*)&W[(size_t)c * D + d4 * 4];
        a0 = fma(a, (double)w.x, a0);
        a1 = fma(a, (double)w.y, a1);
        a2 = fma(a, (double)w.z, a2);
        a3 = fma(a, (double)w.w, a3);
    }
    double* op = &T1[(size_t)e4 * 4];
    op[0] = a0; op[1] = a1; op[2] = a2; op[3] = a3;
}

// ------------------------------------------------------------------
// fused gather + (dx @ W_bot) GEMM + max-over-k + bias + relu, fp64 acc.
// Block = 64 rows (4 points x 16 neighbors) x TN cols. Each wave owns
// exactly one point; max over k collapses via shfl_xor within the wave.
// ------------------------------------------------------------------
template<int C, int D, int TN>
__global__ __launch_bounds__(256) void gemm_max_kernel(
        const float* __restrict__ X, const double* __restrict__ T1,
        const float* __restrict__ W, const float* __restrict__ bias,
        const int* __restrict__ idx, float* __restrict__ O) {
    constexpr int CS  = (C == 3) ? 4 : C + 4;  // 16B-aligned padded stride
    constexpr int LPR = TN / 4;                // lanes per row-group in col dim
    constexpr int TW  = 256 / TN;              // row-groups per wave (= per point)
    constexpr int UR  = TN / 16;               // rows per thread
    __shared__ float Xs[64 * CS];
    __shared__ float Ws[C * TN];
    __shared__ float Xi[4 * CS];
    __shared__ int   idxs[64];

    int tid = threadIdx.x;
    int m0p = blockIdx.x * 4;            // 4 points per block (same batch)
    int n0  = blockIdx.y * TN;
    int b   = m0p >> 11;
    const float* Xb = X + ((size_t)b << 11) * C;
    const float* Wb = W + (size_t)C * D;  // bottom half rows C..2C-1

    if (tid < 64) idxs[tid] = idx[(size_t)m0p * K_ + tid];
    if (tid < 4 * C) {
        int pl = tid / C, c = tid - pl * C;
        Xi[pl * CS + c] = X[(size_t)(m0p + pl) * C + c];
    }
    __syncthreads();

    // gather neighbors, subtract center: dx = x_j - x_i
    if constexpr (C == 3) {
        for (int e = tid; e < 64 * 3; e += 256) {
            int r = e / 3, c = e - r * 3;
            int j = idxs[r];
            Xs[r * CS + c] = Xb[(size_t)j * 3 + c] - Xi[(r >> 4) * CS + c];
        }
    } else {
        constexpr int C4 = C / 4;
        for (int e4 = tid; e4 < 64 * C4; e4 += 256) {
            int r = e4 / C4, c4 = e4 - r * C4;
            int j = idxs[r];
            float4 v  = *(const float4*)&Xb[(size_t)j * C + c4 * 4];
            float4 xc = *(const float4*)&Xi[(r >> 4) * CS + c4 * 4];
            v.x -= xc.x; v.y -= xc.y; v.z -= xc.z; v.w -= xc.w;
            *(float4*)&Xs[r * CS + c4 * 4] = v;
        }
    }
    for (int e = tid; e < C * TN; e += 256) {
        int cr = e / TN;
        Ws[e] = Wb[(size_t)cr * D + n0 + (e - cr * TN)];
    }
    __syncthreads();

    int tx = tid % LPR, ty = tid / LPR;
    int m = m0p + ty / TW;

    const double* t1p = &T1[(size_t)m * D + n0 + tx * 4];
    double t10 = t1p[0], t11 = t1p[1], t12 = t1p[2], t13 = t1p[3];
    double acc[UR][4];
#pragma unroll
    for (int u = 0; u < UR; ++u) {
        acc[u][0] = t10; acc[u][1] = t11; acc[u][2] = t12; acc[u][3] = t13;
    }

#pragma unroll 2
    for (int c = 0; c < C; ++c) {
        float4 w = *(const float4*)&Ws[c * TN + tx * 4];
        double w0 = (double)w.x, w1 = (double)w.y, w2 = (double)w.z, w3 = (double)w.w;
#pragma unroll
        for (int u = 0; u < UR; ++u) {
            double a = (double)Xs[(ty * UR + u) * CS + c];
            acc[u][0] = fma(a, w0, acc[u][0]);
            acc[u][1] = fma(a, w1, acc[u][1]);
            acc[u][2] = fma(a, w2, acc[u][2]);
            acc[u][3] = fma(a, w3, acc[u][3]);
        }
    }

    // max over this thread's UR rows
    double bm[4];
#pragma unroll
    for (int q = 0; q < 4; ++q) bm[q] = acc[0][q];
#pragma unroll
    for (int u = 1; u < UR; ++u)
#pragma unroll
        for (int q = 0; q < 4; ++q) bm[q] = fmax(bm[q], acc[u][q]);

    // max across the TW row-groups of this wave (one point per wave)
#pragma unroll
    for (int off = LPR; off < LPR * TW; off <<= 1)
#pragma unroll
        for (int q = 0; q < 4; ++q)
            bm[q] = fmax(bm[q], __shfl_xor(bm[q], off, 64));

    if (ty % TW == 0) {
        float4 bi = *(const float4*)&bias[n0 + tx * 4];
        float4 o;
        o.x = (float)fmax(bm[0] + (double)bi.x, 0.0);
        o.y = (float)fmax(bm[1] + (double)bi.y, 0.0);
        o.z = (float)fmax(bm[2] + (double)bi.z, 0.0);
        o.w = (float)fmax(bm[3] + (double)bi.w, 0.0);
        *(float4*)&O[(size_t)m * D + n0 + tx * 4] = o;
    }
}

// ------------------------------------------------------------------
// reconstructor MLP: 64 -> relu 128 -> relu 64 -> 3.  32 points/block.
// ------------------------------------------------------------------
__global__ __launch_bounds__(256) void recon_kernel(const float* __restrict__ U,
        const float* __restrict__ W0, const float* __restrict__ b0,
        const float* __restrict__ W1, const float* __restrict__ b1,
        const float* __restrict__ W2, const float* __restrict__ b2,
        float* __restrict__ O) {
    __shared__ float F[32 * 68];
    __shared__ float H1[128 * 33];
    __shared__ float H2[64 * 33];
    __shared__ float W2s[64 * 4];
    __shared__ float b0s[128], b1s[64], b2s[4];

    int tid = threadIdx.x;
    int m0 = blockIdx.x * 32;

    {   // stage input features (32 pts x 64 ch)
        const float4* src = (const float4*)(U + (size_t)m0 * 64);
        for (int e4 = tid; e4 < 32 * 16; e4 += 256) {
            int p = e4 >> 4, c4 = e4 & 15;
            *(float4*)&F[p * 68 + c4 * 4] = src[e4];
        }
    }
    if (tid < 192) W2s[(tid / 3) * 4 + (tid % 3)] = W2[tid];
    if (tid < 128) b0s[tid] = b0[tid];
    else if (tid < 192) b1s[tid - 128] = b1[tid - 128];
    else if (tid == 192) { b2s[0] = b2[0]; b2s[1] = b2[1]; b2s[2] = b2[2]; }
    __syncthreads();

    int p = tid >> 3, s = tid & 7;     // 32 points x 8 lanes

    // layer 1: d = s*4 + q*32 + i
    float acc[16];
#pragma unroll
    for (int q = 0; q < 16; ++q) acc[q] = 0.f;
    for (int c = 0; c < 64; ++c) {
        float a = F[p * 68 + c];
#pragma unroll
        for (int q = 0; q < 4; ++q) {
            float4 w = *(const float4*)&W0[c * 128 + s * 4 + q * 32];
            acc[q * 4 + 0] = fmaf(a, w.x, acc[q * 4 + 0]);
            acc[q * 4 + 1] = fmaf(a, w.y, acc[q * 4 + 1]);
            acc[q * 4 + 2] = fmaf(a, w.z, acc[q * 4 + 2]);
            acc[q * 4 + 3] = fmaf(a, w.w, acc[q * 4 + 3]);
        }
    }
#pragma unroll
    for (int q = 0; q < 4; ++q)
#pragma unroll
        for (int i2 = 0; i2 < 4; ++i2) {
            int dd = s * 4 + q * 32 + i2;
            H1[dd * 33 + p] = fmaxf(acc[q * 4 + i2] + b0s[dd], 0.f);
        }
    __syncthreads();

    // layer 2
    float a2[8];
#pragma unroll
    for (int q = 0; q < 8; ++q) a2[q] = 0.f;
    for (int c = 0; c < 128; ++c) {
        float a = H1[c * 33 + p];
#pragma unroll
        for (int q = 0; q < 2; ++q) {
            float4 w = *(const float4*)&W1[c * 64 + s * 4 + q * 32];
            a2[q * 4 + 0] = fmaf(a, w.x, a2[q * 4 + 0]);
            a2[q * 4 + 1] = fmaf(a, w.y, a2[q * 4 + 1]);
            a2[q * 4 + 2] = fmaf(a, w.z, a2[q * 4 + 2]);
            a2[q * 4 + 3] = fmaf(a, w.w, a2[q * 4 + 3]);
        }
    }
#pragma unroll
    for (int q = 0; q < 2; ++q)
#pragma unroll
        for (int i2 = 0; i2 < 4; ++i2) {
            int dd = s * 4 + q * 32 + i2;
            H2[dd * 33 + p] = fmaxf(a2[q * 4 + i2] + b1s[dd], 0.f);
        }
    __syncthreads();

    // layer 3: 96 threads -> 32 points x 3 outputs
    if (tid < 96) {
        int p3 = tid / 3, d3 = tid - p3 * 3;
        float av = 0.f;
#pragma unroll
        for (int c = 0; c < 64; ++c)
            av = fmaf(H2[c * 33 + p3], W2s[c * 4 + d3], av);
        O[(size_t)(m0 + p3) * 3 + d3] = av + b2s[d3];
    }
}

// ------------------------------------------------------------------
extern "C" void kernel_launch(void* const* d_in, const int* in_sizes, int n_in,
                              void* d_out, int out_size, void* d_ws, size_t ws_size,
                              hipStream_t stream) {
    const float* x   = (const float*)d_in[0];
    const float* W0  = (const float*)d_in[1];
    const float* b0  = (const float*)d_in[2];
    const float* W1  = (const float*)d_in[3];
    const float* b1  = (const float*)d_in[4];
    const float* W2  = (const float*)d_in[5];
    const float* b2  = (const float*)d_in[6];
    const float* Wup = (const float*)d_in[7];
    const float* bup = (const float*)d_in[8];
    const float* Wr0 = (const float*)d_in[9];
    const float* br0 = (const float*)d_in[10];
    const float* Wr1 = (const float*)d_in[11];
    const float* br1 = (const float*)d_in[12];
    const float* Wr2 = (const float*)d_in[13];
    const float* br2 = (const float*)d_in[14];
    float* out = (float*)d_out;

    char* ws = (char*)d_ws;
    size_t o = 0;
    auto alloc = [&](size_t nbytes) {
        void* pp = ws + o;
        o += (nbytes + 255) & ~(size_t)255;
        return pp;
    };
    float*  X1  = (float*)alloc((size_t)M_ * 32 * 4);
    float*  X2  = (float*)alloc((size_t)M_ * 32 * 4);
    float*  X3  = (float*)alloc((size_t)M_ * 64 * 4);
    double* T1  = (double*)alloc((size_t)M_ * 256 * 8);
    float*  H   = (float*)alloc((size_t)M_ * 256 * 4);
    int*    idxb = (int*)alloc((size_t)M_ * 16 * 4);

    // layer 0 (C=3 -> 32)
    knn_kernel<3><<<512, 256, 0, stream>>>(x, idxb);
    t1_kernel<3, 32><<<M_ * 8 / 256, 256, 0, stream>>>(x, W0, T1);
    gemm_max_kernel<3, 32, 32><<<dim3(M_ / 4, 1), 256, 0, stream>>>(x, T1, W0, b0, idxb, X1);
    // layer 1 (32 -> 32)
    knn_kernel<32><<<512, 256, 0, stream>>>(X1, idxb);
    t1_kernel<32, 32><<<M_ * 8 / 256, 256, 0, stream>>>(X1, W1, T1);
    gemm_max_kernel<32, 32, 32><<<dim3(M_ / 4, 1), 256, 0, stream>>>(X1, T1, W1, b1, idxb, X2);
    // layer 2 (32 -> 64)
    knn_kernel<32><<<512, 256, 0, stream>>>(X2, idxb);
    t1_kernel<32, 64><<<M_ * 16 / 256, 256, 0, stream>>>(X2, W2, T1);
    gemm_max_kernel<32, 64, 64><<<dim3(M_ / 4, 1), 256, 0, stream>>>(X2, T1, W2, b2, idxb, X3);
    // NodeShuffle (64 -> 256), reshape is a flat no-op
    knn_kernel<64><<<512, 256, 0, stream>>>(X3, idxb);
    t1_kernel<64, 256><<<M_ * 64 / 256, 256, 0, stream>>>(X3, Wup, T1);
    gemm_max_kernel<64, 256, 64><<<dim3(M_ / 4, 4), 256, 0, stream>>>(X3, T1, Wup, bup, idxb, H);
    // reconstructor
    recon_kernel<<<2048, 256, 0, stream>>>(H, Wr0, br0, Wr1, br1, Wr2, br2, out);
}

// Round 4
// 1154.801 us; speedup vs baseline: 1.1245x; 1.1245x over previous
//
#include <hip/hip_runtime.h>

#define B_ 8
#define N_ 2048
#define K_ 16
#define M_ (B_*N_)

__device__ __forceinline__ unsigned long long kmin(unsigned long long a, unsigned long long b) {
    return a < b ? a : b;
}
__device__ __forceinline__ float  ffma(float a, float b, float c)  { return fmaf(a, b, c); }
__device__ __forceinline__ double ffma(double a, double b, double c){ return fma(a, b, c); }
__device__ __forceinline__ float  fmx(float a, float b)  { return fmaxf(a, b); }
__device__ __forceinline__ double fmx(double a, double b){ return fmax(a, b); }

// ------------------------------------------------------------------
// kNN: per (b,i) the 16 smallest ||x_i - x_j||^2 (direct differences).
// 32 rows/block, 8 lanes/row; per-lane sorted top-16 (u64 keys), merged
// across the 8 lanes with a shuffle + bitonic network. XCD chunk-swizzle
// so each XCD's L2 holds exactly one batch.
// ------------------------------------------------------------------
template<int C>
__global__ __launch_bounds__(256, 2) void knn_kernel(const float* __restrict__ X,
                                                     int* __restrict__ idx_out) {
    constexpr int ROWS = 32, TPR = 8, TJ = 128;
    constexpr int SJ = (C == 3) ? 4 : (C + 4);
    __shared__ float xj[TJ * SJ];

    int tid = threadIdx.x;
    int rlocal = tid / TPR;
    int r = tid & (TPR - 1);
    int sb = (blockIdx.x & 7) * (M_ / ROWS / 8) + (blockIdx.x >> 3);  // XCD swizzle
    int m = sb * ROWS + rlocal;
    int b = m >> 11;
    int i = m & (N_ - 1);

    const float* xrow = X + (size_t)m * C;
    float xi[C];
#pragma unroll
    for (int c = 0; c < C; ++c) xi[c] = xrow[c];

    unsigned long long t[16];
#pragma unroll
    for (int q = 0; q < 16; ++q) t[q] = ~0ull;

    const float* Xb = X + (size_t)b * N_ * C;

    for (int jt = 0; jt < N_ / TJ; ++jt) {
        __syncthreads();
        if constexpr (C == 3) {
            for (int e = tid; e < TJ * 3; e += 256)
                xj[(e / 3) * 4 + (e % 3)] = Xb[jt * TJ * 3 + e];
        } else {
            constexpr int C4 = C / 4;
            const float4* src = (const float4*)(Xb + (size_t)jt * TJ * C);
            for (int e4 = tid; e4 < TJ * C4; e4 += 256) {
                int jl = e4 / C4, c4 = e4 % C4;
                *(float4*)&xj[jl * SJ + c4 * 4] = src[e4];
            }
        }
        __syncthreads();

#pragma unroll 2
        for (int jl = r; jl < TJ; jl += TPR) {
            float s = 0.f;
            if constexpr (C == 3) {
#pragma unroll
                for (int c = 0; c < 3; ++c) {
                    float df = xi[c] - xj[jl * SJ + c];
                    s = fmaf(df, df, s);
                }
            } else {
#pragma unroll
                for (int c4 = 0; c4 < C / 4; ++c4) {
                    float4 v = *(const float4*)&xj[jl * SJ + c4 * 4];
                    float d0 = xi[c4 * 4 + 0] - v.x;
                    float d1 = xi[c4 * 4 + 1] - v.y;
                    float d2 = xi[c4 * 4 + 2] - v.z;
                    float d3 = xi[c4 * 4 + 3] - v.w;
                    s = fmaf(d0, d0, s);
                    s = fmaf(d1, d1, s);
                    s = fmaf(d2, d2, s);
                    s = fmaf(d3, d3, s);
                }
            }
            int jg = jt * TJ + jl;
            unsigned u = __float_as_uint(s);
            u ^= (unsigned)(((int)u >> 31) | 0x80000000);
            unsigned long long key = ((unsigned long long)u << 32) | (unsigned)jg;
            if (jg == i) key = ~0ull;
            if (key < t[15]) {
                t[15] = key;
#pragma unroll
                for (int s2 = 15; s2 > 0; --s2) {
                    unsigned long long a = t[s2 - 1], bb = t[s2];
                    bool sw = bb < a;
                    t[s2 - 1] = sw ? bb : a;
                    t[s2]     = sw ? a : bb;
                }
            }
        }
    }

#pragma unroll
    for (int msk = 1; msk <= 4; msk <<= 1) {
        unsigned long long o[16];
#pragma unroll
        for (int q = 0; q < 16; ++q)
            o[q] = __shfl_xor((unsigned long long)t[q], msk, 64);
        unsigned long long nt[16];
#pragma unroll
        for (int q = 0; q < 16; ++q) nt[q] = kmin(t[q], o[15 - q]);
#pragma unroll
        for (int s2 = 8; s2 >= 1; s2 >>= 1) {
#pragma unroll
            for (int q = 0; q < 16; ++q) {
                if (!(q & s2)) {
                    unsigned long long a = nt[q], bb = nt[q | s2];
                    bool sw = bb < a;
                    nt[q]      = sw ? bb : a;
                    nt[q | s2] = sw ? a : bb;
                }
            }
        }
#pragma unroll
        for (int q = 0; q < 16; ++q) t[q] = nt[q];
    }

    if (r == 0) {
        int* op = idx_out + (size_t)m * K_;
#pragma unroll
        for (int q = 0; q < 16; ++q) op[q] = (int)(unsigned)(t[q] & 0xffffffffull);
    }
}

// ------------------------------------------------------------------
// Fused EdgeConv: seed = x_i @ W_top (in-kernel, ACC precision), then
// gather dx = x_j - x_i, acc += dx @ W_bot, max over k, bias, relu.
// Block = 4 points x 16 neighbors (64 rows); inner loop over D/TN
// column tiles reuses the staged dx. Each wave owns one point; max
// collapses via shfl_xor. XCD chunk-swizzle (batch per XCD).
// ------------------------------------------------------------------
template<int C, int D, int TN, typename ACC>
__global__ __launch_bounds__(256) void edge_kernel(
        const float* __restrict__ X, const float* __restrict__ W,
        const float* __restrict__ bias, const int* __restrict__ idx,
        float* __restrict__ O) {
    constexpr int NTILE = D / TN;
    constexpr int CS  = (C == 3) ? 4 : C + 4;
    constexpr int LPR = TN / 4;
    constexpr int TW  = 256 / TN;
    constexpr int UR  = TN / 16;
    constexpr int TN4 = TN / 4;
    __shared__ float Xs[64 * CS];
    __shared__ float Xi[4 * CS];
    __shared__ float Ws[2 * C * TN];
    __shared__ int   idxs[64];

    int tid = threadIdx.x;
    int sb  = (blockIdx.x & 7) * (M_ / 4 / 8) + (blockIdx.x >> 3);  // XCD swizzle
    int m0p = sb * 4;
    int b   = m0p >> 11;
    const float* Xb = X + ((size_t)b << 11) * C;

    if (tid < 64) idxs[tid] = idx[(size_t)m0p * K_ + tid];
    if (tid < 4 * C) {
        int pl = tid / C, c = tid - pl * C;
        Xi[pl * CS + c] = X[(size_t)(m0p + pl) * C + c];
    }
    __syncthreads();

    // gather neighbors, subtract center: dx = x_j - x_i
    if constexpr (C == 3) {
        for (int e = tid; e < 64 * 3; e += 256) {
            int r = e / 3, c = e - r * 3;
            int j = idxs[r];
            Xs[r * CS + c] = Xb[(size_t)j * 3 + c] - Xi[(r >> 4) * CS + c];
        }
    } else {
        constexpr int C4 = C / 4;
        for (int e4 = tid; e4 < 64 * C4; e4 += 256) {
            int r = e4 / C4, c4 = e4 - r * C4;
            int j = idxs[r];
            float4 v  = *(const float4*)&Xb[(size_t)j * C + c4 * 4];
            float4 xc = *(const float4*)&Xi[(r >> 4) * CS + c4 * 4];
            v.x -= xc.x; v.y -= xc.y; v.z -= xc.z; v.w -= xc.w;
            *(float4*)&Xs[r * CS + c4 * 4] = v;
        }
    }

    int tx = tid % LPR, ty = tid / LPR;
    int p  = ty / TW;
    int m  = m0p + p;

    for (int t = 0; t < NTILE; ++t) {
        int n0 = t * TN;
        // stage W tile: rows 0..2C-1, cols n0..n0+TN-1
        for (int e4 = tid; e4 < 2 * C * TN4; e4 += 256) {
            int rr = e4 / TN4, j4 = e4 - rr * TN4;
            *(float4*)&Ws[rr * TN + j4 * 4] = *(const float4*)&W[(size_t)rr * D + n0 + j4 * 4];
        }
        __syncthreads();   // dx (t==0) + W tile ready

        // seed: x_i @ W_top, ascending c (matches ref's first-C dims)
        ACC s0 = 0, s1 = 0, s2 = 0, s3 = 0;
#pragma unroll 4
        for (int c = 0; c < C; ++c) {
            ACC a = (ACC)Xi[p * CS + c];
            float4 w = *(const float4*)&Ws[c * TN + tx * 4];
            s0 = ffma(a, (ACC)w.x, s0);
            s1 = ffma(a, (ACC)w.y, s1);
            s2 = ffma(a, (ACC)w.z, s2);
            s3 = ffma(a, (ACC)w.w, s3);
        }
        ACC acc[UR][4];
#pragma unroll
        for (int u = 0; u < UR; ++u) {
            acc[u][0] = s0; acc[u][1] = s1; acc[u][2] = s2; acc[u][3] = s3;
        }

        // dx @ W_bot, ascending c (matches ref's second-C dims)
        if constexpr (C == 3) {
#pragma unroll
            for (int c = 0; c < 3; ++c) {
                float4 w = *(const float4*)&Ws[(3 + c) * TN + tx * 4];
                ACC w0 = (ACC)w.x, w1 = (ACC)w.y, w2 = (ACC)w.z, w3 = (ACC)w.w;
#pragma unroll
                for (int u = 0; u < UR; ++u) {
                    ACC a = (ACC)Xs[(ty * UR + u) * CS + c];
                    acc[u][0] = ffma(a, w0, acc[u][0]);
                    acc[u][1] = ffma(a, w1, acc[u][1]);
                    acc[u][2] = ffma(a, w2, acc[u][2]);
                    acc[u][3] = ffma(a, w3, acc[u][3]);
                }
            }
        } else {
#pragma unroll 2
            for (int c4 = 0; c4 < C / 4; ++c4) {
                float4 xv[UR];
#pragma unroll
                for (int u = 0; u < UR; ++u)
                    xv[u] = *(const float4*)&Xs[(ty * UR + u) * CS + c4 * 4];
#pragma unroll
                for (int cc = 0; cc < 4; ++cc) {
                    float4 w = *(const float4*)&Ws[(C + c4 * 4 + cc) * TN + tx * 4];
                    ACC w0 = (ACC)w.x, w1 = (ACC)w.y, w2 = (ACC)w.z, w3 = (ACC)w.w;
#pragma unroll
                    for (int u = 0; u < UR; ++u) {
                        float av = (cc == 0) ? xv[u].x : (cc == 1) ? xv[u].y
                                 : (cc == 2) ? xv[u].z : xv[u].w;
                        ACC a = (ACC)av;
                        acc[u][0] = ffma(a, w0, acc[u][0]);
                        acc[u][1] = ffma(a, w1, acc[u][1]);
                        acc[u][2] = ffma(a, w2, acc[u][2]);
                        acc[u][3] = ffma(a, w3, acc[u][3]);
                    }
                }
            }
        }

        // max over this thread's UR rows, then across the wave's row-groups
        ACC bm[4];
#pragma unroll
        for (int q = 0; q < 4; ++q) bm[q] = acc[0][q];
#pragma unroll
        for (int u = 1; u < UR; ++u)
#pragma unroll
            for (int q = 0; q < 4; ++q) bm[q] = fmx(bm[q], acc[u][q]);
#pragma unroll
        for (int off = LPR; off < LPR * TW; off <<= 1)
#pragma unroll
            for (int q = 0; q < 4; ++q)
                bm[q] = fmx(bm[q], (ACC)__shfl_xor(bm[q], off, 64));

        if (ty % TW == 0) {
            float4 bi = *(const float4*)&bias[n0 + tx * 4];
            float4 o;
            o.x = (float)fmx(bm[0] + (ACC)bi.x, (ACC)0);
            o.y = (float)fmx(bm[1] + (ACC)bi.y, (ACC)0);
            o.z = (float)fmx(bm[2] + (ACC)bi.z, (ACC)0);
            o.w = (float)fmx(bm[3] + (ACC)bi.w, (ACC)0);
            *(float4*)&O[(size_t)m * D + n0 + tx * 4] = o;
        }
        __syncthreads();   // all reads of Ws done before next tile overwrites
    }
}

// ------------------------------------------------------------------
// reconstructor MLP: 64 -> relu 128 -> relu 64 -> 3.  32 points/block.
// ------------------------------------------------------------------
__global__ __launch_bounds__(256) void recon_kernel(const float* __restrict__ U,
        const float* __restrict__ W0, const float* __restrict__ b0,
        const float* __restrict__ W1, const float* __restrict__ b1,
        const float* __restrict__ W2, const float* __restrict__ b2,
        float* __restrict__ O) {
    __shared__ float F[32 * 68];
    __shared__ float H1[128 * 33];
    __shared__ float H2[64 * 33];
    __shared__ float W2s[64 * 4];
    __shared__ float b0s[128], b1s[64], b2s[4];

    int tid = threadIdx.x;
    int m0 = blockIdx.x * 32;

    {
        const float4* src = (const float4*)(U + (size_t)m0 * 64);
        for (int e4 = tid; e4 < 32 * 16; e4 += 256) {
            int p = e4 >> 4, c4 = e4 & 15;
            *(float4*)&F[p * 68 + c4 * 4] = src[e4];
        }
    }
    if (tid < 192) W2s[(tid / 3) * 4 + (tid % 3)] = W2[tid];
    if (tid < 128) b0s[tid] = b0[tid];
    else if (tid < 192) b1s[tid - 128] = b1[tid - 128];
    else if (tid == 192) { b2s[0] = b2[0]; b2s[1] = b2[1]; b2s[2] = b2[2]; }
    __syncthreads();

    int p = tid >> 3, s = tid & 7;

    float acc[16];
#pragma unroll
    for (int q = 0; q < 16; ++q) acc[q] = 0.f;
    for (int c = 0; c < 64; ++c) {
        float a = F[p * 68 + c];
#pragma unroll
        for (int q = 0; q < 4; ++q) {
            float4 w = *(const float4*)&W0[c * 128 + s * 4 + q * 32];
            acc[q * 4 + 0] = fmaf(a, w.x, acc[q * 4 + 0]);
            acc[q * 4 + 1] = fmaf(a, w.y, acc[q * 4 + 1]);
            acc[q * 4 + 2] = fmaf(a, w.z, acc[q * 4 + 2]);
            acc[q * 4 + 3] = fmaf(a, w.w, acc[q * 4 + 3]);
        }
    }
#pragma unroll
    for (int q = 0; q < 4; ++q)
#pragma unroll
        for (int i2 = 0; i2 < 4; ++i2) {
            int dd = s * 4 + q * 32 + i2;
            H1[dd * 33 + p] = fmaxf(acc[q * 4 + i2] + b0s[dd], 0.f);
        }
    __syncthreads();

    float a2[8];
#pragma unroll
    for (int q = 0; q < 8; ++q) a2[q] = 0.f;
    for (int c = 0; c < 128; ++c) {
        float a = H1[c * 33 + p];
#pragma unroll
        for (int q = 0; q < 2; ++q) {
            float4 w = *(const float4*)&W1[c * 64 + s * 4 + q * 32];
            a2[q * 4 + 0] = fmaf(a, w.x, a2[q * 4 + 0]);
            a2[q * 4 + 1] = fmaf(a, w.y, a2[q * 4 + 1]);
            a2[q * 4 + 2] = fmaf(a, w.z, a2[q * 4 + 2]);
            a2[q * 4 + 3] = fmaf(a, w.w, a2[q * 4 + 3]);
        }
    }
#pragma unroll
    for (int q = 0; q < 2; ++q)
#pragma unroll
        for (int i2 = 0; i2 < 4; ++i2) {
            int dd = s * 4 + q * 32 + i2;
            H2[dd * 33 + p] = fmaxf(a2[q * 4 + i2] + b1s[dd], 0.f);
        }
    __syncthreads();

    if (tid < 96) {
        int p3 = tid / 3, d3 = tid - p3 * 3;
        float av = 0.f;
#pragma unroll
        for (int c = 0; c < 64; ++c)
            av = fmaf(H2[c * 33 + p3], W2s[c * 4 + d3], av);
        O[(size_t)(m0 + p3) * 3 + d3] = av + b2s[d3];
    }
}

// ------------------------------------------------------------------
extern "C" void kernel_launch(void* const* d_in, const int* in_sizes, int n_in,
                              void* d_out, int out_size, void* d_ws, size_t ws_size,
                              hipStream_t stream) {
    const float* x   = (const float*)d_in[0];
    const float* W0  = (const float*)d_in[1];
    const float* b0  = (const float*)d_in[2];
    const float* W1  = (const float*)d_in[3];
    const float* b1  = (const float*)d_in[4];
    const float* W2  = (const float*)d_in[5];
    const float* b2  = (const float*)d_in[6];
    const float* Wup = (const float*)d_in[7];
    const float* bup = (const float*)d_in[8];
    const float* Wr0 = (const float*)d_in[9];
    const float* br0 = (const float*)d_in[10];
    const float* Wr1 = (const float*)d_in[11];
    const float* br1 = (const float*)d_in[12];
    const float* Wr2 = (const float*)d_in[13];
    const float* br2 = (const float*)d_in[14];
    float* out = (float*)d_out;

    char* ws = (char*)d_ws;
    size_t o = 0;
    auto alloc = [&](size_t nbytes) {
        void* pp = ws + o;
        o += (nbytes + 255) & ~(size_t)255;
        return pp;
    };
    float* X1   = (float*)alloc((size_t)M_ * 32 * 4);
    float* X2   = (float*)alloc((size_t)M_ * 32 * 4);
    float* X3   = (float*)alloc((size_t)M_ * 64 * 4);
    float* H    = (float*)alloc((size_t)M_ * 256 * 4);
    int*   idxb = (int*)alloc((size_t)M_ * 16 * 4);

    // layer 0 (C=3 -> 32), f64 accumulate
    knn_kernel<3><<<512, 256, 0, stream>>>(x, idxb);
    edge_kernel<3, 32, 32, double><<<M_ / 4, 256, 0, stream>>>(x, W0, b0, idxb, X1);
    // layer 1 (32 -> 32), f64
    knn_kernel<32><<<512, 256, 0, stream>>>(X1, idxb);
    edge_kernel<32, 32, 32, double><<<M_ / 4, 256, 0, stream>>>(X1, W1, b1, idxb, X2);
    // layer 2 (32 -> 64), f64
    knn_kernel<32><<<512, 256, 0, stream>>>(X2, idxb);
    edge_kernel<32, 64, 64, double><<<M_ / 4, 256, 0, stream>>>(X2, W2, b2, idxb, X3);
    // NodeShuffle (64 -> 256), fp32 accumulate (feeds only the shallow recon MLP)
    knn_kernel<64><<<512, 256, 0, stream>>>(X3, idxb);
    edge_kernel<64, 256, 64, float><<<M_ / 4, 256, 0, stream>>>(X3, Wup, bup, idxb, H);
    // reconstructor
    recon_kernel<<<2048, 256, 0, stream>>>(H, Wr0, br0, Wr1, br1, Wr2, br2, out);
}

// Round 6
// 1115.378 us; speedup vs baseline: 1.1642x; 1.0353x over previous
//
#include <hip/hip_runtime.h>

#define B_ 8
#define N_ 2048
#define K_ 16
#define M_ (B_*N_)

typedef unsigned long long ull;

__device__ __forceinline__ ull kmin(ull a, ull b) { return a < b ? a : b; }

// ------------------------------------------------------------------
// kNN, two-phase register-blocked.
// Phase A: 32x128 distance tile, each thread a 4x4 (i,j) patch from
// transposed LDS (b128 reads both sides). Same ascending-c fmaf chain
// as the passing rounds -> bit-identical distances.
// Phase B: scan S with float4-min fast path; u64 key insert on hit.
// ------------------------------------------------------------------
template<int C>
__global__ __launch_bounds__(256, 2) void knn2_kernel(const float* __restrict__ X,
                                                      int* __restrict__ idx_out) {
    constexpr int TJ = 128;
    constexpr int SJ = TJ + 4;   // 132: padded strides
    constexpr int SS = TJ + 4;
    constexpr int SI = 36;
    __shared__ float xiT[C][SI];
    __shared__ float xjT[C][SJ];
    __shared__ float S[32][SS];

    int tid = threadIdx.x;
    int sb = (blockIdx.x & 7) * (M_ / 32 / 8) + (blockIdx.x >> 3);  // XCD swizzle
    int m0 = sb * 32;
    int b  = m0 >> 11;
    int i0 = m0 & (N_ - 1);
    const float* Xb = X + ((size_t)b << 11) * C;

    // stage xiT (transposed)
    if constexpr (C == 3) {
        if (tid < 96) { int ir = tid / 3, c = tid - ir * 3;
            xiT[c][ir] = X[(size_t)(m0 + ir) * 3 + c]; }
    } else {
        constexpr int C4 = C / 4;
        for (int e4 = tid; e4 < 32 * C4; e4 += 256) {
            int ir = e4 / C4, c4 = e4 - ir * C4;
            float4 v = *(const float4*)&X[(size_t)(m0 + ir) * C + c4 * 4];
            xiT[c4*4+0][ir] = v.x; xiT[c4*4+1][ir] = v.y;
            xiT[c4*4+2][ir] = v.z; xiT[c4*4+3][ir] = v.w;
        }
    }

    ull t[16];
#pragma unroll
    for (int q = 0; q < 16; ++q) t[q] = ~0ull;
    float t15f = __uint_as_float(0x7FFFFFFFu);  // NaN: !(s > t15f) == true until list fills

    int ig = tid >> 5, jl4 = tid & 31;      // phase A ids
    int irow = tid >> 3, r = tid & 7;       // phase B ids
    int i_loc = i0 + irow;

    for (int jt = 0; jt < N_ / TJ; ++jt) {
        __syncthreads();      // previous tile's S/xjT readers done
        // stage xjT transposed
        if constexpr (C == 3) {
            for (int e = tid; e < TJ * 3; e += 256) {
                int jl = e / 3, c = e - jl * 3;
                xjT[c][jl] = Xb[(size_t)jt * TJ * 3 + e];
            }
        } else {
            constexpr int C4 = C / 4;
            for (int e4 = tid; e4 < 32 * C4; e4 += 256) {
                int jb = e4 / C4, c4 = e4 - jb * C4;
                const float* src = &Xb[(size_t)(jt * TJ + jb * 4) * C + c4 * 4];
                float4 v0 = *(const float4*)&src[0];
                float4 v1 = *(const float4*)&src[C];
                float4 v2 = *(const float4*)&src[2 * C];
                float4 v3 = *(const float4*)&src[3 * C];
                *(float4*)&xjT[c4*4+0][jb*4] = make_float4(v0.x, v1.x, v2.x, v3.x);
                *(float4*)&xjT[c4*4+1][jb*4] = make_float4(v0.y, v1.y, v2.y, v3.y);
                *(float4*)&xjT[c4*4+2][jb*4] = make_float4(v0.z, v1.z, v2.z, v3.z);
                *(float4*)&xjT[c4*4+3][jb*4] = make_float4(v0.w, v1.w, v2.w, v3.w);
            }
        }
        __syncthreads();

        // phase A
        float acc[4][4];
#pragma unroll
        for (int u = 0; u < 4; ++u) {
            acc[u][0] = 0.f; acc[u][1] = 0.f; acc[u][2] = 0.f; acc[u][3] = 0.f;
        }
#pragma unroll 4
        for (int c = 0; c < C; ++c) {
            float4 xi4 = *(const float4*)&xiT[c][ig * 4];
            float4 xj4 = *(const float4*)&xjT[c][jl4 * 4];
            float xiv[4] = {xi4.x, xi4.y, xi4.z, xi4.w};
            float xjv[4] = {xj4.x, xj4.y, xj4.z, xj4.w};
#pragma unroll
            for (int u = 0; u < 4; ++u)
#pragma unroll
                for (int v = 0; v < 4; ++v) {
                    float df = xiv[u] - xjv[v];
                    acc[u][v] = fmaf(df, df, acc[u][v]);
                }
        }
#pragma unroll
        for (int u = 0; u < 4; ++u)
            *(float4*)&S[ig * 4 + u][jl4 * 4] =
                make_float4(acc[u][0], acc[u][1], acc[u][2], acc[u][3]);
        __syncthreads();

        // phase B
        int jbase = jt * TJ + r * 16;
#pragma unroll
        for (int w = 0; w < 4; ++w) {
            float4 sv = *(const float4*)&S[irow][r * 16 + w * 4];
            float se[4] = {sv.x, sv.y, sv.z, sv.w};
            float mn = fminf(fminf(se[0], se[1]), fminf(se[2], se[3]));
            if (!(mn > t15f)) {
#pragma unroll
                for (int e = 0; e < 4; ++e) {
                    float s = se[e];
                    if (!(s > t15f)) {
                        int jg = jbase + w * 4 + e;
                        if (jg != i_loc) {
                            unsigned uu = __float_as_uint(s) ^ 0x80000000u;
                            ull key = ((ull)uu << 32) | (unsigned)jg;
                            if (key < t[15]) {
                                t[15] = key;
#pragma unroll
                                for (int s2 = 15; s2 > 0; --s2) {
                                    ull a = t[s2 - 1], bb2 = t[s2];
                                    bool sw = bb2 < a;
                                    t[s2 - 1] = sw ? bb2 : a;
                                    t[s2]     = sw ? a : bb2;
                                }
                                t15f = __uint_as_float((unsigned)(t[15] >> 32) ^ 0x80000000u);
                            }
                        }
                    }
                }
            }
        }
    }

    // merge the 8 lanes' sorted-16 lists (bitonic, as in passing rounds)
#pragma unroll
    for (int msk = 1; msk <= 4; msk <<= 1) {
        ull o[16];
#pragma unroll
        for (int q = 0; q < 16; ++q)
            o[q] = __shfl_xor((ull)t[q], msk, 64);
        ull nt[16];
#pragma unroll
        for (int q = 0; q < 16; ++q) nt[q] = kmin(t[q], o[15 - q]);
#pragma unroll
        for (int s2 = 8; s2 >= 1; s2 >>= 1) {
#pragma unroll
            for (int q = 0; q < 16; ++q) {
                if (!(q & s2)) {
                    ull a = nt[q], bb2 = nt[q | s2];
                    bool sw = bb2 < a;
                    nt[q]      = sw ? bb2 : a;
                    nt[q | s2] = sw ? a : bb2;
                }
            }
        }
#pragma unroll
        for (int q = 0; q < 16; ++q) t[q] = nt[q];
    }

    if (r == 0) {
        int* op = idx_out + (size_t)(m0 + irow) * K_;
#pragma unroll
        for (int q = 0; q < 16; ++q) op[q] = (int)(unsigned)(t[q] & 0xffffffffull);
    }
}

// ------------------------------------------------------------------
// proj: T1NB[m][0:DH] = X @ Wtop cols[doff:doff+DH],
//       T1NB[m][DH:2DH] = X @ Wbot cols[doff:doff+DH], f64 accumulate.
// grid (M/64, 2*DH/64), 64x64 tiles, thread 4x4 f64 acc.
// ------------------------------------------------------------------
template<int C>
__global__ __launch_bounds__(256) void proj_kernel(const float* __restrict__ X,
        const float* __restrict__ W, double* __restrict__ T1NB,
        int Dfull, int DH, int doff) {
    __shared__ float XsT[C][68];
    __shared__ float Bs[C][64];
    int tid = threadIdx.x;
    int m0 = blockIdx.x * 64;
    int n0 = blockIdx.y * 64;

    if constexpr (C == 3) {
        if (tid < 192) { int row = tid / 3, c = tid - row * 3;
            XsT[c][row] = X[(size_t)(m0 + row) * 3 + c]; }
    } else {
        constexpr int C4 = C / 4;
        for (int e4 = tid; e4 < 64 * C4; e4 += 256) {
            int row = e4 / C4, c4 = e4 - row * C4;
            float4 v = *(const float4*)&X[(size_t)(m0 + row) * C + c4 * 4];
            XsT[c4*4+0][row] = v.x; XsT[c4*4+1][row] = v.y;
            XsT[c4*4+2][row] = v.z; XsT[c4*4+3][row] = v.w;
        }
    }
    for (int e = tid; e < C * 64; e += 256) {
        int c = e >> 6, dc = e & 63;
        int n = n0 + dc;
        float wv = (n < DH) ? W[(size_t)c * Dfull + doff + n]
                            : W[(size_t)(C + c) * Dfull + doff + (n - DH)];
        Bs[c][dc] = wv;
    }
    __syncthreads();

    int tx = tid & 15, ty = tid >> 4;
    double acc[4][4];
#pragma unroll
    for (int u = 0; u < 4; ++u) { acc[u][0]=0.0; acc[u][1]=0.0; acc[u][2]=0.0; acc[u][3]=0.0; }

#pragma unroll 4
    for (int c = 0; c < C; ++c) {
        float4 xv = *(const float4*)&XsT[c][ty * 4];
        float4 wv = *(const float4*)&Bs[c][tx * 4];
        double xd[4] = {(double)xv.x, (double)xv.y, (double)xv.z, (double)xv.w};
        double wd[4] = {(double)wv.x, (double)wv.y, (double)wv.z, (double)wv.w};
#pragma unroll
        for (int u = 0; u < 4; ++u)
#pragma unroll
            for (int v = 0; v < 4; ++v)
                acc[u][v] = fma(xd[u], wd[v], acc[u][v]);
    }
#pragma unroll
    for (int u = 0; u < 4; ++u) {
        double* dst = &T1NB[(size_t)(m0 + ty * 4 + u) * (2 * DH) + n0 + tx * 4];
        *(double2*)&dst[0] = make_double2(acc[u][0], acc[u][1]);
        *(double2*)&dst[2] = make_double2(acc[u][2], acc[u][3]);
    }
}

// ------------------------------------------------------------------
// gmax: O[m][doff+d] = relu(max_k (T1[m][d] - NB[m][d] + NB[j_k][d]) + b)
// T1NB rows [T1 | NB], stride 2*DH doubles. fp32 out.
// ------------------------------------------------------------------
template<int DH>
__global__ __launch_bounds__(256) void gmax_kernel(const double* __restrict__ T1NB,
        const int* __restrict__ idx, const float* __restrict__ bias,
        float* __restrict__ O, int Dfull, int doff) {
    constexpr int TPP = DH / 2;
    constexpr int PPB = 256 / TPP;
    __shared__ int idxs[PPB * 16];

    int tid = threadIdx.x;
    int cpx = gridDim.x >> 3;
    int sb = ((int)blockIdx.x & 7) * cpx + ((int)blockIdx.x >> 3);  // XCD swizzle
    int m0 = sb * PPB;

    if (tid < PPB * 16)
        idxs[tid] = idx[(size_t)(m0 + tid / 16) * K_ + (tid & 15)];
    __syncthreads();

    int p = tid / TPP, dh = tid % TPP;
    int d0 = dh * 2;
    int m = m0 + p;
    int b = m >> 11;
    size_t base = (size_t)m * (2 * DH);
    double2 t1  = *(const double2*)&T1NB[base + d0];
    double2 nbi = *(const double2*)&T1NB[base + DH + d0];
    double ba = t1.x - nbi.x, bb = t1.y - nbi.y;
    double ma = -1.0e300, mb = -1.0e300;
    size_t rowb = ((size_t)(b << 11)) * (2 * DH) + DH + d0;
    const int* ip = &idxs[p * 16];
#pragma unroll 4
    for (int k = 0; k < 16; ++k) {
        int j = ip[k];
        double2 q = *(const double2*)&T1NB[rowb + (size_t)j * (2 * DH)];
        ma = fmax(ma, ba + q.x);
        mb = fmax(mb, bb + q.y);
    }
    float2 o;
    o.x = (float)fmax(ma + (double)bias[doff + d0],     0.0);
    o.y = (float)fmax(mb + (double)bias[doff + d0 + 1], 0.0);
    *(float2*)&O[(size_t)m * Dfull + doff + d0] = o;
}

// ------------------------------------------------------------------
// reconstructor MLP: 64 -> relu 128 -> relu 64 -> 3.  32 points/block.
// ------------------------------------------------------------------
__global__ __launch_bounds__(256) void recon_kernel(const float* __restrict__ U,
        const float* __restrict__ W0, const float* __restrict__ b0,
        const float* __restrict__ W1, const float* __restrict__ b1,
        const float* __restrict__ W2, const float* __restrict__ b2,
        float* __restrict__ O) {
    __shared__ float F[32 * 68];
    __shared__ float H1[128 * 33];
    __shared__ float H2[64 * 33];
    __shared__ float W2s[64 * 4];
    __shared__ float b0s[128], b1s[64], b2s[4];

    int tid = threadIdx.x;
    int m0 = blockIdx.x * 32;

    {
        const float4* src = (const float4*)(U + (size_t)m0 * 64);
        for (int e4 = tid; e4 < 32 * 16; e4 += 256) {
            int p = e4 >> 4, c4 = e4 & 15;
            *(float4*)&F[p * 68 + c4 * 4] = src[e4];
        }
    }
    if (tid < 192) W2s[(tid / 3) * 4 + (tid % 3)] = W2[tid];
    if (tid < 128) b0s[tid] = b0[tid];
    else if (tid < 192) b1s[tid - 128] = b1[tid - 128];
    else if (tid == 192) { b2s[0] = b2[0]; b2s[1] = b2[1]; b2s[2] = b2[2]; }
    __syncthreads();

    int p = tid >> 3, s = tid & 7;

    float acc[16];
#pragma unroll
    for (int q = 0; q < 16; ++q) acc[q] = 0.f;
    for (int c = 0; c < 64; ++c) {
        float a = F[p * 68 + c];
#pragma unroll
        for (int q = 0; q < 4; ++q) {
            float4 w = *(const float4*)&W0[c * 128 + s * 4 + q * 32];
            acc[q * 4 + 0] = fmaf(a, w.x, acc[q * 4 + 0]);
            acc[q * 4 + 1] = fmaf(a, w.y, acc[q * 4 + 1]);
            acc[q * 4 + 2] = fmaf(a, w.z, acc[q * 4 + 2]);
            acc[q * 4 + 3] = fmaf(a, w.w, acc[q * 4 + 3]);
        }
    }
#pragma unroll
    for (int q = 0; q < 4; ++q)
#pragma unroll
        for (int i2 = 0; i2 < 4; ++i2) {
            int dd = s * 4 + q * 32 + i2;
            H1[dd * 33 + p] = fmaxf(acc[q * 4 + i2] + b0s[dd], 0.f);
        }
    __syncthreads();

    float a2[8];
#pragma unroll
    for (int q = 0; q < 8; ++q) a2[q] = 0.f;
    for (int c = 0; c < 128; ++c) {
        float a = H1[c * 33 + p];
#pragma unroll
        for (int q = 0; q < 2; ++q) {
            float4 w = *(const float4*)&W1[c * 64 + s * 4 + q * 32];
            a2[q * 4 + 0] = fmaf(a, w.x, a2[q * 4 + 0]);
            a2[q * 4 + 1] = fmaf(a, w.y, a2[q * 4 + 1]);
            a2[q * 4 + 2] = fmaf(a, w.z, a2[q * 4 + 2]);
            a2[q * 4 + 3] = fmaf(a, w.w, a2[q * 4 + 3]);
        }
    }
#pragma unroll
    for (int q = 0; q < 2; ++q)
#pragma unroll
        for (int i2 = 0; i2 < 4; ++i2) {
            int dd = s * 4 + q * 32 + i2;
            H2[dd * 33 + p] = fmaxf(a2[q * 4 + i2] + b1s[dd], 0.f);
        }
    __syncthreads();

    if (tid < 96) {
        int p3 = tid / 3, d3 = tid - p3 * 3;
        float av = 0.f;
#pragma unroll
        for (int c = 0; c < 64; ++c)
            av = fmaf(H2[c * 33 + p3], W2s[c * 4 + d3], av);
        O[(size_t)(m0 + p3) * 3 + d3] = av + b2s[d3];
    }
}

// ------------------------------------------------------------------
extern "C" void kernel_launch(void* const* d_in, const int* in_sizes, int n_in,
                              void* d_out, int out_size, void* d_ws, size_t ws_size,
                              hipStream_t stream) {
    const float* x   = (const float*)d_in[0];
    const float* W0  = (const float*)d_in[1];
    const float* b0  = (const float*)d_in[2];
    const float* W1  = (const float*)d_in[3];
    const float* b1  = (const float*)d_in[4];
    const float* W2  = (const float*)d_in[5];
    const float* b2  = (const float*)d_in[6];
    const float* Wup = (const float*)d_in[7];
    const float* bup = (const float*)d_in[8];
    const float* Wr0 = (const float*)d_in[9];
    const float* br0 = (const float*)d_in[10];
    const float* Wr1 = (const float*)d_in[11];
    const float* br1 = (const float*)d_in[12];
    const float* Wr2 = (const float*)d_in[13];
    const float* br2 = (const float*)d_in[14];
    float* out = (float*)d_out;

    char* ws = (char*)d_ws;
    size_t o = 0;
    auto alloc = [&](size_t nbytes) {
        void* pp = ws + o;
        o += (nbytes + 255) & ~(size_t)255;
        return pp;
    };
    float*  X1   = (float*)alloc((size_t)M_ * 32 * 4);
    float*  X2   = (float*)alloc((size_t)M_ * 32 * 4);
    float*  X3   = (float*)alloc((size_t)M_ * 64 * 4);
    float*  H    = (float*)alloc((size_t)M_ * 256 * 4);
    int*    idxb = (int*)alloc((size_t)M_ * 16 * 4);
    double* T1NB = (double*)alloc((size_t)M_ * 256 * 8);

    // layer 0 (3 -> 32)
    knn2_kernel<3><<<512, 256, 0, stream>>>(x, idxb);
    proj_kernel<3><<<dim3(M_ / 64, 1), 256, 0, stream>>>(x, W0, T1NB, 32, 32, 0);
    gmax_kernel<32><<<M_ / 16, 256, 0, stream>>>(T1NB, idxb, b0, X1, 32, 0);
    // layer 1 (32 -> 32)
    knn2_kernel<32><<<512, 256, 0, stream>>>(X1, idxb);
    proj_kernel<32><<<dim3(M_ / 64, 1), 256, 0, stream>>>(X1, W1, T1NB, 32, 32, 0);
    gmax_kernel<32><<<M_ / 16, 256, 0, stream>>>(T1NB, idxb, b1, X2, 32, 0);
    // layer 2 (32 -> 64)
    knn2_kernel<32><<<512, 256, 0, stream>>>(X2, idxb);
    proj_kernel<32><<<dim3(M_ / 64, 2), 256, 0, stream>>>(X2, W2, T1NB, 64, 64, 0);
    gmax_kernel<64><<<M_ / 8, 256, 0, stream>>>(T1NB, idxb, b2, X3, 64, 0);
    // NodeShuffle (64 -> 256) in two column halves; reshape is a flat no-op
    knn2_kernel<64><<<512, 256, 0, stream>>>(X3, idxb);
    proj_kernel<64><<<dim3(M_ / 64, 4), 256, 0, stream>>>(X3, Wup, T1NB, 256, 128, 0);
    gmax_kernel<128><<<M_ / 4, 256, 0, stream>>>(T1NB, idxb, bup, H, 256, 0);
    proj_kernel<64><<<dim3(M_ / 64, 4), 256, 0, stream>>>(X3, Wup, T1NB, 256, 128, 128);
    gmax_kernel<128><<<M_ / 4, 256, 0, stream>>>(T1NB, idxb, bup, H, 256, 128);
    // reconstructor
    recon_kernel<<<2048, 256, 0, stream>>>(H, Wr0, br0, Wr1, br1, Wr2, br2, out);
}